// Round 7
// baseline (270.164 us; speedup 1.0000x reference)
//
#include <hip/hip_runtime.h>
#include <math.h>

#define KE_C     14.3996f
#define ALPHA_C  0.3f
#define CUTOFF_C 10.0f
#define TWO_PI_C 6.283185307179586f
#define ASPL     32
#define NK2      512           // padded half-k slot count (510 real)
#define NREAL    2048          // real-space blocks

typedef float vfloat4 __attribute__((ext_vector_type(4)));
typedef int   vint4   __attribute__((ext_vector_type(4)));

// fast erfc: Abramowitz & Stegun 7.1.26, |abs err| < 1.5e-7
__device__ __forceinline__ float fast_erfc(float x) {
    float t = __builtin_amdgcn_rcpf(fmaf(0.3275911f, x, 1.0f));
    float p = fmaf(t, 1.061405429f, -1.453152027f);
    p = fmaf(t, p, 1.421413741f);
    p = fmaf(t, p, -0.284496736f);
    p = fmaf(t, p, 0.254829592f);
    return t * p * __expf(-x * x);
}

// sin/cos of 2*pi*x via raw HW ops (input in revolutions)
__device__ __forceinline__ void sincos_rev(float x, float* s, float* c) {
    float f = __builtin_amdgcn_fractf(x);
    *s = __builtin_amdgcn_sinf(f);
    *c = __builtin_amdgcn_cosf(f);
}

// 3x3 inverse (row-major); returns det
__device__ __forceinline__ float inv3x3(const float* c, float* inv) {
    float a00 = c[0], a01 = c[1], a02 = c[2];
    float a10 = c[3], a11 = c[4], a12 = c[5];
    float a20 = c[6], a21 = c[7], a22 = c[8];
    float det = a00 * (a11 * a22 - a12 * a21)
              - a01 * (a10 * a22 - a12 * a20)
              + a02 * (a10 * a21 - a11 * a20);
    float id = 1.0f / det;
    inv[0] = (a11 * a22 - a12 * a21) * id;   // inv[0][0]
    inv[1] = (a02 * a21 - a01 * a22) * id;   // inv[0][1]
    inv[2] = (a01 * a12 - a02 * a11) * id;
    inv[3] = (a12 * a20 - a10 * a22) * id;
    inv[4] = (a00 * a22 - a02 * a20) * id;
    inv[5] = (a02 * a10 - a00 * a12) * id;
    inv[6] = (a10 * a21 - a11 * a20) * id;
    inv[7] = (a01 * a20 - a00 * a21) * id;
    inv[8] = (a00 * a11 - a01 * a10) * id;
    return det;
}

// ---------------- setup kernel: atoms + bounds + half-k compaction ----------------
// blocks [0, NA): per-atom phase (fractional coords, 2pi cancels), packed q|mol, self-int
// block NA: molecule segment bounds; block NA+1: half-space k list
__global__ __launch_bounds__(256) void k_setup(const float* __restrict__ R,
                                               const float* __restrict__ q,
                                               const int* __restrict__ idx_m,
                                               const float* __restrict__ cell,
                                               const float* __restrict__ kvecs,
                                               float4* __restrict__ S4,
                                               unsigned int* __restrict__ QP,
                                               float* __restrict__ SI,
                                               int* __restrict__ bounds,
                                               float4* __restrict__ KH,
                                               int* __restrict__ cnt,
                                               int natoms, int nmol, int nk, int NA) {
    int bid = blockIdx.x;
    int tid = threadIdx.x;
    if (bid < NA) {
        __shared__ float si[64];
        if (tid < 64) si[tid] = 0.0f;
        __syncthreads();
        int a = bid * 256 + tid;
        if (a < natoms) {
            int m = idx_m[a];
            float inv[9];
            inv3x3(cell + m * 9, inv);
            float r0 = R[3 * a], r1 = R[3 * a + 1], r2 = R[3 * a + 2];
            // s_rev[d] = sum_e inv[e][d] * R[e]   (revolutions; 2pi cancels)
            float s0 = inv[0] * r0 + inv[3] * r1 + inv[6] * r2;
            float s1 = inv[1] * r0 + inv[4] * r1 + inv[7] * r2;
            float s2 = inv[2] * r0 + inv[5] * r1 + inv[8] * r2;
            float qa = q[a];
            S4[a] = make_float4(s0, s1, s2, qa);
            QP[a] = (__float_as_uint(qa) & ~63u) | (unsigned int)(m & 63);
            atomicAdd(&si[m & 63], qa * qa);
        }
        __syncthreads();
        if (tid < 64) atomicAdd(&SI[tid], si[tid]);
    } else if (bid == NA) {
        int m = tid;
        if (m <= nmol) {
            int lo = 0, hi = natoms;
            while (lo < hi) {
                int mid = (lo + hi) >> 1;
                if (idx_m[mid] < m) lo = mid + 1; else hi = mid;
            }
            bounds[m] = lo;
        }
    } else {
        for (int k = tid; k < nk; k += 256) {
            float gx = kvecs[3 * k], gy = kvecs[3 * k + 1], gz = kvecs[3 * k + 2];
            bool pos = (gx > 0.5f) ||
                       (fabsf(gx) < 0.5f && (gy > 0.5f ||
                        (fabsf(gy) < 0.5f && gz > 0.5f)));
            if (pos) {
                int s = atomicAdd(cnt, 1);
                KH[s] = make_float4(gx, gy, gz, 0.0f);
            }
        }
    }
}

// ---------------- fused main kernel: recip/real blocks interleaved by parity ----------------
__global__ __launch_bounds__(256) void k_main(const float4* __restrict__ S4,
                                              const float4* __restrict__ KH,
                                              const int* __restrict__ bounds,
                                              float* __restrict__ QR,
                                              float* __restrict__ QI, int nrecip,
                                              const float* __restrict__ Rij,
                                              const int* __restrict__ idx_i,
                                              const int* __restrict__ idx_j,
                                              const unsigned int* __restrict__ QP,
                                              float* __restrict__ YRpad, int npairs) {
    __shared__ float acc[4][64];
    int tid = threadIdx.x;
    int bid = blockIdx.x;

    // interleave: odd bids (below 2*nrecip) are recip, even are real; rest real
    bool recip = (bid < 2 * nrecip) && (bid & 1);
    int idx = (bid < 2 * nrecip) ? (bid >> 1) : (bid - nrecip);

    if (recip) {
        // ---- reciprocal: 2 half-k slots per thread, wave-uniform atom loads ----
        int m  = idx / ASPL;
        int ac = idx % ASPL;
        int s0 = bounds[m], s1 = bounds[m + 1];
        int per = (s1 - s0 + ASPL - 1) / ASPL;
        int a0 = s0 + ac * per;
        int a1 = min(a0 + per, s1);
        float4 g0 = KH[tid];            // pad slots zero -> harmless
        float4 g1 = KH[tid + 256];
        float qr0 = 0.f, qi0 = 0.f, qr1 = 0.f, qi1 = 0.f;
#pragma unroll 4
        for (int t = a0; t < a1; ++t) {
            float4 s = S4[t];           // uniform address -> scalar load
            float ph0 = fmaf(g0.x, s.x, fmaf(g0.y, s.y, g0.z * s.z));
            float ph1 = fmaf(g1.x, s.x, fmaf(g1.y, s.y, g1.z * s.z));
            float sn0, cs0, sn1, cs1;
            sincos_rev(ph0, &sn0, &cs0);
            sincos_rev(ph1, &sn1, &cs1);
            qr0 = fmaf(s.w, cs0, qr0);
            qi0 = fmaf(s.w, sn0, qi0);
            qr1 = fmaf(s.w, cs1, qr1);
            qi1 = fmaf(s.w, sn1, qi1);
        }
        atomicAdd(&QR[m * NK2 + tid], qr0);
        atomicAdd(&QI[m * NK2 + tid], qi0);
        atomicAdd(&QR[m * NK2 + tid + 256], qr1);
        atomicAdd(&QI[m * NK2 + tid + 256], qi1);
    } else {
        // ---- real space: 4-pair chunks, grid-stride, software-pipelined ----
        int wave = tid >> 6;
        ((float*)acc)[tid] = 0.0f;
        __syncthreads();
        const float sqa = 0.5477225575051661f;      // sqrt(0.3)
        const float frcut = fast_erfc(sqa * CUTOFF_C) / CUTOFF_C;
        int nchunk = npairs >> 2;
        int stride = NREAL * 256;
        int c = idx * 256 + tid;
        vint4 ii, jj; vfloat4 A, B, C;
        if (c < nchunk) {
            int p = c << 2;
            ii = *(const vint4*)(idx_i + p);
            jj = *(const vint4*)(idx_j + p);
            const vfloat4* r4 = (const vfloat4*)(Rij + 3 * p);
            A = r4[0]; B = r4[1]; C = r4[2];
        }
        while (c < nchunk) {
            int cn = c + stride;
            vint4 ii2, jj2; vfloat4 A2, B2, C2;
            if (cn < nchunk) {          // prefetch next iteration's streams
                int p = cn << 2;
                ii2 = *(const vint4*)(idx_i + p);
                jj2 = *(const vint4*)(idx_j + p);
                const vfloat4* r4 = (const vfloat4*)(Rij + 3 * p);
                A2 = r4[0]; B2 = r4[1]; C2 = r4[2];
            }
            unsigned int ui0 = QP[ii.x], ui1 = QP[ii.y], ui2 = QP[ii.z], ui3 = QP[ii.w];
            unsigned int uj0 = QP[jj.x], uj1 = QP[jj.y], uj2 = QP[jj.z], uj3 = QP[jj.w];
#define PAIR(xx, yy, zz, ui, uj)                                              \
            {                                                                 \
                float d2 = fmaf(xx, xx, fmaf(yy, yy, (zz) * (zz)));           \
                float rd = __builtin_amdgcn_rsqf(d2);                         \
                float d = d2 * rd;                                            \
                float f = fast_erfc(sqa * d) * rd - frcut;                    \
                f = (d2 <= CUTOFF_C * CUTOFF_C) ? f : 0.0f;                   \
                float qi_ = __uint_as_float((ui) & ~63u);                     \
                float qj_ = __uint_as_float((uj) & ~63u);                     \
                atomicAdd(&acc[wave][(ui) & 63u], qi_ * qj_ * f);             \
            }
            PAIR(A.x, A.y, A.z, ui0, uj0)
            PAIR(A.w, B.x, B.y, ui1, uj1)
            PAIR(B.z, B.w, C.x, ui2, uj2)
            PAIR(C.y, C.z, C.w, ui3, uj3)
#undef PAIR
            c = cn; ii = ii2; jj = jj2; A = A2; B = B2; C = C2;
        }
        // tail (npairs not multiple of 4)
        if (bid == 0 && tid == 0) {
            for (int p = (npairs >> 2) << 2; p < npairs; ++p) {
                float x = Rij[3 * p], y = Rij[3 * p + 1], z = Rij[3 * p + 2];
                float d2 = fmaf(x, x, fmaf(y, y, z * z));
                if (d2 <= CUTOFF_C * CUTOFF_C) {
                    float rd = __builtin_amdgcn_rsqf(d2);
                    float d = d2 * rd;
                    unsigned int ui = QP[idx_i[p]], uj = QP[idx_j[p]];
                    float qi_ = __uint_as_float(ui & ~63u);
                    float qj_ = __uint_as_float(uj & ~63u);
                    atomicAdd(&acc[0][ui & 63u],
                              qi_ * qj_ * (fast_erfc(sqa * d) * rd - frcut));
                }
            }
        }
        __syncthreads();
        if (tid < 64) {
            float v = acc[0][tid] + acc[1][tid] + acc[2][tid] + acc[3][tid];
            atomicAdd(&YRpad[tid * 16], v);
        }
    }
}

// ---------------- finalize per molecule (half-space k, weight 2; inline inverse) ----------
__global__ __launch_bounds__(256) void k_final(const float4* __restrict__ KH,
                                               const int* __restrict__ cnt,
                                               const float* __restrict__ cell,
                                               const float* __restrict__ QR,
                                               const float* __restrict__ QI,
                                               const float* __restrict__ YRpad,
                                               const float* __restrict__ SI,
                                               float* __restrict__ out) {
    int m = blockIdx.x;
    int tid = threadIdx.x;
    __shared__ float wsum[4];
    float inv[9];
    float det = inv3x3(cell + m * 9, inv);
    int nhalf = cnt[0];
    float acc = 0.0f;
    for (int k = tid; k < nhalf; k += 256) {
        float4 g = KH[k];
        // kv[e] = 2pi * sum_d g[d] * inv[e][d]
        float kv0 = TWO_PI_C * (g.x * inv[0] + g.y * inv[1] + g.z * inv[2]);
        float kv1 = TWO_PI_C * (g.x * inv[3] + g.y * inv[4] + g.z * inv[5]);
        float kv2 = TWO_PI_C * (g.x * inv[6] + g.y * inv[7] + g.z * inv[8]);
        float ksq = kv0 * kv0 + kv1 * kv1 + kv2 * kv2;
        float qr = QR[m * NK2 + k], qi = QI[m * NK2 + k];
        acc += (qr * qr + qi * qi) * __expf(-0.25f / ALPHA_C * ksq) / ksq;
    }
#pragma unroll
    for (int off = 32; off > 0; off >>= 1) acc += __shfl_down(acc, off, 64);
    if ((tid & 63) == 0) wsum[tid >> 6] = acc;
    __syncthreads();
    if (tid == 0) {
        float s = 2.0f * (wsum[0] + wsum[1] + wsum[2] + wsum[3]);   // +g/-g symmetry
        float pref = TWO_PI_C / fabsf(det);
        float self_c = sqrtf(ALPHA_C / 3.14159265358979323846f);
        out[m] = 0.5f * KE_C * YRpad[m * 16] + KE_C * (pref * s - self_c * SI[m]);
    }
}

extern "C" void kernel_launch(void* const* d_in, const int* in_sizes, int n_in,
                              void* d_out, int out_size, void* d_ws, size_t ws_size,
                              hipStream_t stream) {
    const float* q     = (const float*)d_in[0];   // [A,1]
    const float* Rij   = (const float*)d_in[1];   // [P,3]
    const float* R     = (const float*)d_in[2];   // [A,3]
    const float* cell  = (const float*)d_in[3];   // [M,3,3]
    const float* kvecs = (const float*)d_in[4];   // [K,3]
    const int*   idx_m = (const int*)d_in[5];     // [A]
    const int*   idx_i = (const int*)d_in[6];     // [P]
    const int*   idx_j = (const int*)d_in[7];     // [P]

    int natoms = in_sizes[0];
    int npairs = in_sizes[1] / 3;
    int nmol   = in_sizes[3] / 9;
    int nk     = in_sizes[4] / 3;
    float* out = (float*)d_out;

    // workspace layout (float offsets; S4/KH 16B-aligned)
    float*  W      = (float*)d_ws;
    int*    bounds = (int*)W;                                  // 80 ints (padded to 16B)
    float4* S4     = (float4*)(W + 80);                        // natoms float4
    unsigned int* QP = (unsigned int*)(W + 80 + 4 * (size_t)natoms); // natoms u32
    size_t  zoff   = 80 + 5 * (size_t)natoms;
    zoff = (zoff + 3) & ~(size_t)3;                            // 16B align
    float4* KH     = (float4*)(W + zoff);                      // NK2 float4
    float*  QR     = W + zoff + 4 * NK2;                       // nmol*NK2
    float*  QI     = QR + (size_t)nmol * NK2;                  // nmol*NK2
    float*  SI     = QI + (size_t)nmol * NK2;                  // 64
    float*  YRpad  = SI + 64;                                  // 64*16
    int*    cnt    = (int*)(YRpad + 64 * 16);                  // 4
    size_t zero_bytes = (4 * NK2 + (size_t)2 * nmol * NK2 + 64 + 64 * 16 + 4) * sizeof(float);
    (void)hipMemsetAsync(KH, 0, zero_bytes, stream);

    int NA = (natoms + 255) / 256;
    int nrecip = nmol * ASPL;                                  // 2048
    k_setup<<<NA + 2, 256, 0, stream>>>(R, q, idx_m, cell, kvecs, S4, QP, SI,
                                        bounds, KH, cnt, natoms, nmol, nk, NA);
    k_main <<<nrecip + NREAL, 256, 0, stream>>>(S4, KH, bounds, QR, QI, nrecip,
                                                Rij, idx_i, idx_j, QP, YRpad, npairs);
    k_final<<<nmol, 256, 0, stream>>>(KH, cnt, cell, QR, QI, YRpad, SI, out);
}

// Round 8
// 240.554 us; speedup vs baseline: 1.1231x; 1.1231x over previous
//
#include <hip/hip_runtime.h>
#include <math.h>

#define KE_C     14.3996f
#define ALPHA_C  0.3f
#define CUTOFF_C 10.0f
#define TWO_PI_C 6.283185307179586f
#define ASPL     32
#define NK2      512           // padded half-k slot count (510 real)
#define NREAL    2048          // real-space blocks (8 blocks/CU)

typedef float vfloat4 __attribute__((ext_vector_type(4)));
typedef int   vint4   __attribute__((ext_vector_type(4)));

// sin/cos of 2*pi*x via raw HW ops (input in revolutions)
__device__ __forceinline__ void sincos_rev(float x, float* s, float* c) {
    float f = __builtin_amdgcn_fractf(x);
    *s = __builtin_amdgcn_sinf(f);
    *c = __builtin_amdgcn_cosf(f);
}

// 3x3 inverse (row-major); returns det
__device__ __forceinline__ float inv3x3(const float* c, float* inv) {
    float a00 = c[0], a01 = c[1], a02 = c[2];
    float a10 = c[3], a11 = c[4], a12 = c[5];
    float a20 = c[6], a21 = c[7], a22 = c[8];
    float det = a00 * (a11 * a22 - a12 * a21)
              - a01 * (a10 * a22 - a12 * a20)
              + a02 * (a10 * a21 - a11 * a20);
    float id = 1.0f / det;
    inv[0] = (a11 * a22 - a12 * a21) * id;
    inv[1] = (a02 * a21 - a01 * a22) * id;
    inv[2] = (a01 * a12 - a02 * a11) * id;
    inv[3] = (a12 * a20 - a10 * a22) * id;
    inv[4] = (a00 * a22 - a02 * a20) * id;
    inv[5] = (a02 * a10 - a00 * a12) * id;
    inv[6] = (a10 * a21 - a11 * a20) * id;
    inv[7] = (a01 * a20 - a00 * a21) * id;
    inv[8] = (a00 * a11 - a01 * a10) * id;
    return det;
}

// ---------------- setup: atoms + bounds + half-k compaction (merged) ----------------
__global__ __launch_bounds__(256) void k_setup(const float* __restrict__ R,
                                               const float* __restrict__ q,
                                               const int* __restrict__ idx_m,
                                               const float* __restrict__ cell,
                                               const float* __restrict__ kvecs,
                                               float4* __restrict__ S4,
                                               float2* __restrict__ QM,
                                               float* __restrict__ SI,
                                               int* __restrict__ bounds,
                                               float4* __restrict__ KH,
                                               int* __restrict__ cnt,
                                               int natoms, int nmol, int nk, int NA) {
    int bid = blockIdx.x;
    int tid = threadIdx.x;
    if (bid < NA) {
        __shared__ float si[64];
        if (tid < 64) si[tid] = 0.0f;
        __syncthreads();
        int a = bid * 256 + tid;
        if (a < natoms) {
            int m = idx_m[a];
            float inv[9];
            inv3x3(cell + m * 9, inv);
            float r0 = R[3 * a], r1 = R[3 * a + 1], r2 = R[3 * a + 2];
            // s_rev[d] = sum_e inv[e][d] * R[e]   (revolutions; 2pi cancels)
            float s0 = inv[0] * r0 + inv[3] * r1 + inv[6] * r2;
            float s1 = inv[1] * r0 + inv[4] * r1 + inv[7] * r2;
            float s2 = inv[2] * r0 + inv[5] * r1 + inv[8] * r2;
            float qa = q[a];
            S4[a] = make_float4(s0, s1, s2, qa);
            QM[a] = make_float2(qa, __int_as_float(m));
            atomicAdd(&si[m & 63], qa * qa);
        }
        __syncthreads();
        if (tid < 64) atomicAdd(&SI[tid], si[tid]);
    } else if (bid == NA) {
        int m = tid;
        if (m <= nmol) {
            int lo = 0, hi = natoms;
            while (lo < hi) {
                int mid = (lo + hi) >> 1;
                if (idx_m[mid] < m) lo = mid + 1; else hi = mid;
            }
            bounds[m] = lo;
        }
    } else {
        for (int k = tid; k < nk; k += 256) {
            float gx = kvecs[3 * k], gy = kvecs[3 * k + 1], gz = kvecs[3 * k + 2];
            bool pos = (gx > 0.5f) ||
                       (fabsf(gx) < 0.5f && (gy > 0.5f ||
                        (fabsf(gy) < 0.5f && gz > 0.5f)));
            if (pos) {
                int s = atomicAdd(cnt, 1);
                KH[s] = make_float4(gx, gy, gz, 0.0f);
            }
        }
    }
}

// ---------------- recip: 2 half-k slots/thread, wave-uniform atom loads ----------------
__global__ __launch_bounds__(256) void k_recip(const float4* __restrict__ S4,
                                               const float4* __restrict__ KH,
                                               const int* __restrict__ bounds,
                                               float* __restrict__ QR,
                                               float* __restrict__ QI) {
    int tid = threadIdx.x;
    int bid = blockIdx.x;
    int m  = bid / ASPL;
    int ac = bid % ASPL;
    int s0 = bounds[m], s1 = bounds[m + 1];
    int per = (s1 - s0 + ASPL - 1) / ASPL;
    int a0 = s0 + ac * per;
    int a1 = min(a0 + per, s1);
    float4 g0 = KH[tid];            // pad slots zero -> harmless
    float4 g1 = KH[tid + 256];
    float qr0 = 0.f, qi0 = 0.f, qr1 = 0.f, qi1 = 0.f;
#pragma unroll 4
    for (int t = a0; t < a1; ++t) {
        float4 s = S4[t];           // uniform address -> scalar load
        float ph0 = fmaf(g0.x, s.x, fmaf(g0.y, s.y, g0.z * s.z));
        float ph1 = fmaf(g1.x, s.x, fmaf(g1.y, s.y, g1.z * s.z));
        float sn0, cs0, sn1, cs1;
        sincos_rev(ph0, &sn0, &cs0);
        sincos_rev(ph1, &sn1, &cs1);
        qr0 = fmaf(s.w, cs0, qr0);
        qi0 = fmaf(s.w, sn0, qi0);
        qr1 = fmaf(s.w, cs1, qr1);
        qi1 = fmaf(s.w, sn1, qi1);
    }
    atomicAdd(&QR[m * NK2 + tid], qr0);
    atomicAdd(&QI[m * NK2 + tid], qi0);
    atomicAdd(&QR[m * NK2 + tid + 256], qr1);
    atomicAdd(&QI[m * NK2 + tid + 256], qi1);
}

// ---------------- real space: R2-exact structure (measured best: 88 us) ----------------
__global__ __launch_bounds__(256, 8) void k_real(const float* __restrict__ Rij,
                                                 const int* __restrict__ idx_i,
                                                 const int* __restrict__ idx_j,
                                                 const float2* __restrict__ QM,
                                                 float* __restrict__ YRpad, int npairs) {
    __shared__ float acc[4][64];            // per-wave private accumulators
    int tid = threadIdx.x;
    int wave = tid >> 6;
    acc[wave][tid & 63] = 0.0f;
    __syncthreads();
    const float sqa = 0.5477225575051661f;  // sqrt(0.3)
    const float frcut = erfcf(sqa * CUTOFF_C) / CUTOFF_C;
    int nchunk = npairs >> 2;
    int stride = NREAL * 256;
    for (int c = blockIdx.x * 256 + tid; c < nchunk; c += stride) {
        int p = c << 2;
        vint4 ii = *(const vint4*)(idx_i + p);
        vint4 jj = *(const vint4*)(idx_j + p);
        const vfloat4* r4 = (const vfloat4*)(Rij + 3 * p);
        vfloat4 ra = r4[0], rb = r4[1], rc = r4[2];
        float x0 = ra.x, y0 = ra.y, z0 = ra.z;
        float x1 = ra.w, y1 = rb.x, z1 = rb.y;
        float x2 = rb.z, y2 = rb.w, z2 = rc.x;
        float x3 = rc.y, y3 = rc.z, z3 = rc.w;
        float2 qi0 = QM[ii.x], qi1 = QM[ii.y], qi2 = QM[ii.z], qi3 = QM[ii.w];
        float2 qj0 = QM[jj.x], qj1 = QM[jj.y], qj2 = QM[jj.z], qj3 = QM[jj.w];
        float d0 = sqrtf(x0 * x0 + y0 * y0 + z0 * z0);
        float d1 = sqrtf(x1 * x1 + y1 * y1 + z1 * z1);
        float d2 = sqrtf(x2 * x2 + y2 * y2 + z2 * z2);
        float d3 = sqrtf(x3 * x3 + y3 * y3 + z3 * z3);
        if (d0 <= CUTOFF_C)
            atomicAdd(&acc[wave][__float_as_int(qi0.y) & 63],
                      qi0.x * qj0.x * (erfcf(sqa * d0) / d0 - frcut));
        if (d1 <= CUTOFF_C)
            atomicAdd(&acc[wave][__float_as_int(qi1.y) & 63],
                      qi1.x * qj1.x * (erfcf(sqa * d1) / d1 - frcut));
        if (d2 <= CUTOFF_C)
            atomicAdd(&acc[wave][__float_as_int(qi2.y) & 63],
                      qi2.x * qj2.x * (erfcf(sqa * d2) / d2 - frcut));
        if (d3 <= CUTOFF_C)
            atomicAdd(&acc[wave][__float_as_int(qi3.y) & 63],
                      qi3.x * qj3.x * (erfcf(sqa * d3) / d3 - frcut));
    }
    // tail (npairs not multiple of 4)
    if (blockIdx.x == 0 && tid == 0) {
        for (int p = (npairs >> 2) << 2; p < npairs; ++p) {
            float x = Rij[3 * p], y = Rij[3 * p + 1], z = Rij[3 * p + 2];
            float d = sqrtf(x * x + y * y + z * z);
            if (d <= CUTOFF_C) {
                float2 qi = QM[idx_i[p]];
                float2 qj = QM[idx_j[p]];
                atomicAdd(&acc[0][__float_as_int(qi.y) & 63],
                          qi.x * qj.x * (erfcf(sqa * d) / d - frcut));
            }
        }
    }
    __syncthreads();
    if (tid < 64) {
        float v = acc[0][tid] + acc[1][tid] + acc[2][tid] + acc[3][tid];
        atomicAdd(&YRpad[tid * 16], v);     // 64 distinct cache lines
    }
}

// ---------------- finalize per molecule (half-space k, weight 2; inline inverse) --------
__global__ __launch_bounds__(256) void k_final(const float4* __restrict__ KH,
                                               const int* __restrict__ cnt,
                                               const float* __restrict__ cell,
                                               const float* __restrict__ QR,
                                               const float* __restrict__ QI,
                                               const float* __restrict__ YRpad,
                                               const float* __restrict__ SI,
                                               float* __restrict__ out) {
    int m = blockIdx.x;
    int tid = threadIdx.x;
    __shared__ float wsum[4];
    float inv[9];
    float det = inv3x3(cell + m * 9, inv);
    int nhalf = cnt[0];
    float acc = 0.0f;
    for (int k = tid; k < nhalf; k += 256) {
        float4 g = KH[k];
        float kv0 = TWO_PI_C * (g.x * inv[0] + g.y * inv[1] + g.z * inv[2]);
        float kv1 = TWO_PI_C * (g.x * inv[3] + g.y * inv[4] + g.z * inv[5]);
        float kv2 = TWO_PI_C * (g.x * inv[6] + g.y * inv[7] + g.z * inv[8]);
        float ksq = kv0 * kv0 + kv1 * kv1 + kv2 * kv2;
        float qr = QR[m * NK2 + k], qi = QI[m * NK2 + k];
        acc += (qr * qr + qi * qi) * __expf(-0.25f / ALPHA_C * ksq) / ksq;
    }
#pragma unroll
    for (int off = 32; off > 0; off >>= 1) acc += __shfl_down(acc, off, 64);
    if ((tid & 63) == 0) wsum[tid >> 6] = acc;
    __syncthreads();
    if (tid == 0) {
        float s = 2.0f * (wsum[0] + wsum[1] + wsum[2] + wsum[3]);   // +g/-g symmetry
        float pref = TWO_PI_C / fabsf(det);
        float self_c = sqrtf(ALPHA_C / 3.14159265358979323846f);
        out[m] = 0.5f * KE_C * YRpad[m * 16] + KE_C * (pref * s - self_c * SI[m]);
    }
}

extern "C" void kernel_launch(void* const* d_in, const int* in_sizes, int n_in,
                              void* d_out, int out_size, void* d_ws, size_t ws_size,
                              hipStream_t stream) {
    const float* q     = (const float*)d_in[0];   // [A,1]
    const float* Rij   = (const float*)d_in[1];   // [P,3]
    const float* R     = (const float*)d_in[2];   // [A,3]
    const float* cell  = (const float*)d_in[3];   // [M,3,3]
    const float* kvecs = (const float*)d_in[4];   // [K,3]
    const int*   idx_m = (const int*)d_in[5];     // [A]
    const int*   idx_i = (const int*)d_in[6];     // [P]
    const int*   idx_j = (const int*)d_in[7];     // [P]

    int natoms = in_sizes[0];
    int npairs = in_sizes[1] / 3;
    int nmol   = in_sizes[3] / 9;
    int nk     = in_sizes[4] / 3;
    float* out = (float*)d_out;

    // workspace layout (float offsets; S4/KH 16B-, QM 8B-aligned)
    float*  W      = (float*)d_ws;
    int*    bounds = (int*)W;                                  // 80 ints
    float4* S4     = (float4*)(W + 80);                        // natoms float4
    float2* QM     = (float2*)(W + 80 + 4 * (size_t)natoms);   // natoms float2
    size_t  zoff   = 80 + 6 * (size_t)natoms;
    zoff = (zoff + 3) & ~(size_t)3;                            // 16B align
    float4* KH     = (float4*)(W + zoff);                      // NK2 float4
    float*  QR     = W + zoff + 4 * NK2;                       // nmol*NK2
    float*  QI     = QR + (size_t)nmol * NK2;                  // nmol*NK2
    float*  SI     = QI + (size_t)nmol * NK2;                  // 64
    float*  YRpad  = SI + 64;                                  // 64*16
    int*    cnt    = (int*)(YRpad + 64 * 16);                  // 4
    size_t zero_bytes = (4 * NK2 + (size_t)2 * nmol * NK2 + 64 + 64 * 16 + 4) * sizeof(float);
    (void)hipMemsetAsync(KH, 0, zero_bytes, stream);

    int NA = (natoms + 255) / 256;
    k_setup<<<NA + 2, 256, 0, stream>>>(R, q, idx_m, cell, kvecs, S4, QM, SI,
                                        bounds, KH, cnt, natoms, nmol, nk, NA);
    k_recip<<<nmol * ASPL, 256, 0, stream>>>(S4, KH, bounds, QR, QI);
    k_real <<<NREAL, 256, 0, stream>>>(Rij, idx_i, idx_j, QM, YRpad, npairs);
    k_final<<<nmol, 256, 0, stream>>>(KH, cnt, cell, QR, QI, YRpad, SI, out);
}